// Round 11
// baseline (892.338 us; speedup 1.0000x reference)
//
#include <hip/hip_runtime.h>

typedef float v16f __attribute__((ext_vector_type(16)));
typedef unsigned short ushort_t;
typedef unsigned char uchar_t;
typedef long long ll_t;

#define HH 768
#define WW 768
#define CH 3
#define KS 24
#define HC 745
#define WC 745
#define NP 256
#define XH 384
#define XW 384

#define NBX 24            // ceil(745/32)
#define NBY 187           // ceil(745/4)
#define NBLK (NBX*NBY)    // 4488
#define BROWS 4
#define BCOLS 32
#define NSTEP 27          // K=1728 in 64-wide slices (8 octets each)
#define NCAND 8
#define NGRID (8*1152)    // XCD-banded launch (some idle)

// async global->LDS DMA; LDS dest = wave-uniform base + lane*size (global addr per-lane)
__device__ __forceinline__ void gload16(const uchar_t* g, uchar_t* l) {
    __builtin_amdgcn_global_load_lds(
        (const __attribute__((address_space(1))) unsigned int*)(const void*)g,
        (__attribute__((address_space(3))) unsigned int*)(void*)l, 16, 0, 0);
}
__device__ __forceinline__ void gload4(const uchar_t* g, uchar_t* l) {
    __builtin_amdgcn_global_load_lds(
        (const __attribute__((address_space(1))) unsigned int*)(const void*)g,
        (__attribute__((address_space(3))) unsigned int*)(void*)l, 4, 0, 0);
}
__device__ __forceinline__ ushort_t f2bf(float f) {
    union { __bf16 h; ushort_t u; } cv; cv.h = (__bf16)f; return cv.u;
}
__device__ __forceinline__ float bf2f(ushort_t u) {
    union { unsigned u; float f; } cv; cv.u = ((unsigned)u) << 16; return cv.f;
}
// fp32 -> OCP e4m3fn (RNE for normals; grid-round for subnormals). Screen-only precision.
__device__ __forceinline__ uchar_t f2e4m3(float f) {
    unsigned u = __float_as_uint(f);
    unsigned s = (u >> 24) & 0x80;
    float a = fabsf(f);
    if (a < 0.0078125f) {
        int q = (int)(a * 512.0f + 0.5f);
        return (uchar_t)(s | (unsigned)q);
    }
    int e = (int)((u >> 23) & 0xFF);
    unsigned m = (u >> 20) & 7;
    unsigned rest = u & 0xFFFFF;
    if (rest > 0x80000 || (rest == 0x80000 && (m & 1))) { m++; if (m == 8) { m = 0; e++; } }
    int e8 = e - 120;
    if (e8 <= 0) { int q = (int)(a * 512.0f + 0.5f); if (q > 7) q = 7; return (uchar_t)(s | q); }
    if (e8 > 15) return (uchar_t)(s | 0x7E);
    return (uchar_t)(s | ((unsigned)e8 << 3) | m);
}

// -------------------- prep kernels --------------------

__global__ void k_colsum(const float* __restrict__ y, float* __restrict__ ksum,
                         float* __restrict__ ksum2) {
    int idx = blockIdx.x * 256 + threadIdx.x;
    if (idx >= HH * WW) return;
    float a = y[idx], b = y[idx + HH * WW], c = y[idx + 2 * HH * WW];
    ksum[idx]  = a + b + c;
    ksum2[idx] = a * a + b * b + c * c;
}

__global__ void k_hsum(const float* __restrict__ ksum, const float* __restrict__ ksum2,
                       float* __restrict__ h1, float* __restrict__ h2) {
    int idx = blockIdx.x * 256 + threadIdx.x;
    if (idx >= HH * WC) return;
    int h = idx / WC, w = idx % WC;
    const float* r  = ksum  + h * WW + w;
    const float* r2 = ksum2 + h * WW + w;
    float s = 0.f, s2 = 0.f;
    #pragma unroll
    for (int j = 0; j < KS; j++) { s += r[j]; s2 += r2[j]; }
    h1[idx] = s; h2[idx] = s2;
}

// bf16 maps are ONLY used for the approximate pre-screen; k_rescore recomputes exactly.
__global__ void k_vsum(const float* __restrict__ h1, const float* __restrict__ h2,
                       ushort_t* __restrict__ s1m, ushort_t* __restrict__ ivm) {
    int idx = blockIdx.x * 256 + threadIdx.x;
    if (idx >= HC * WC) return;
    int r = idx / WC, w = idx % WC;
    float s = 0.f, s2 = 0.f;
    #pragma unroll
    for (int i = 0; i < KS; i++) { s += h1[(r + i) * WC + w]; s2 += h2[(r + i) * WC + w]; }
    float d2 = s2 - s * s * (1.0f / 576.0f);
    s1m[idx] = f2bf(s);
    ivm[idx] = f2bf(rsqrtf(fmaxf(d2, 1e-20f)));
}

__global__ void k_meanx(const float* __restrict__ x, float* __restrict__ mx) {
    int p = blockIdx.x;
    int pr = p >> 4, pc = p & 15;
    float s = 0.f;
    for (int e = threadIdx.x; e < CH * KS * KS; e += 256) {
        int c = e / (KS * KS); int rem = e % (KS * KS);
        int i = rem / KS, j = rem % KS;
        s += x[(c * XH + pr * KS + i) * XW + pc * KS + j];
    }
    __shared__ float red[256];
    red[threadIdx.x] = s; __syncthreads();
    for (int st = 128; st > 0; st >>= 1) {
        if (threadIdx.x < st) red[threadIdx.x] += red[threadIdx.x + st];
        __syncthreads();
    }
    if (threadIdx.x == 0) mx[p] = red[0] * (1.0f / 1728.0f);
}

// fp8 patch matrix, K-MAJOR: bmk[octet 0..215][pat 0..255][8B]
__global__ void k_bmat8(const float* __restrict__ x, uchar_t* __restrict__ bmk) {
    int p = blockIdx.x; int pr = p >> 4, pc = p & 15;
    for (int e = threadIdx.x; e < CH * KS * KS; e += 256) {
        int c = e / (KS * KS), rem = e % (KS * KS), i = rem / KS, j = rem % KS;
        bmk[(e >> 3) * (NP * 8) + p * 8 + (e & 7)] =
            f2e4m3(x[(c * XH + pr * KS + i) * XW + pc * KS + j]);
    }
}

// 4 column-shifted fp8 copies: y4[S][c][r][t] = fp8(ydec[c][r][t+S]), S in 0..3, 0-pad OOB.
__global__ void k_y4(const float* __restrict__ yd, uchar_t* __restrict__ y4) {
    int idx = blockIdx.x * 256 + threadIdx.x;
    if (idx >= 4 * 3 * HH * (WW / 4)) return;
    int q = idx % (WW / 4); int rem = idx / (WW / 4);
    int r = rem % HH; rem /= HH;
    int c = rem % 3; int S = rem / 3;
    const float* src = yd + (c * HH + r) * WW;
    union { uchar_t u[4]; unsigned v; } o;
    #pragma unroll
    for (int qq = 0; qq < 4; qq++) {
        int t = q * 4 + qq + S;
        o.u[qq] = f2e4m3(t < WW ? src[t] : 0.f);
    }
    ((unsigned*)(y4 + ((size_t)(S * 3 + c) * HH + r) * WW))[q] = o.v;
}

// -------------------- main MFMA correlation kernel (fp8, double-buffered) --------------------
// 256 thr (4 waves); XCD-banded flat grid (R10). Tile = 128 pos x 128 pat; wave tile 64x64
// of mfma_f32_32x32x16_fp8_fp8. SINGLE __syncthreads per slice + double-buffered LDS:
// the barrier's implicit vmcnt(0) drain IS the producer-consumer sync — slice s+1's DMA
// (issued right after the barrier) overlaps the whole slice-s compute phase.

__global__ __launch_bounds__(256, 4) void k_corr(
    const uchar_t* __restrict__ y4, const uchar_t* __restrict__ bmk,
    const ushort_t* __restrict__ s1m, const ushort_t* __restrict__ ivm,
    const float* __restrict__ mx, ushort_t* __restrict__ ps16)
{
    // ---- XCD-band mapping (heuristic blk%8 -> XCD; wrong mapping only costs speed) ----
    const int xcd = blockIdx.x & 7;
    const int idx = blockIdx.x >> 3;
    const int bstart = (187 * xcd) >> 3;
    const int bcnt = ((187 * (xcd + 1)) >> 3) - bstart;
    const int local_by = idx / 48;
    if (local_by >= bcnt) return;                    // idle filler block (before any barrier)
    const int rem = idx - local_by * 48;
    const int z = rem / 24;                          // patch half
    const int bx = rem - z * 24;
    const int by = bstart + local_by;

    __shared__ __align__(16) uchar_t Ab[2 * 8192];   // 2 x 8KB [oct][pos 0..127][8B]
    __shared__ __align__(16) uchar_t Bb[2 * 8192];   // 2 x 8KB [oct][pat 0..127][8B]
    float* red = (float*)Ab;                         // epilogue-only alias (post-sync)

    const int tid = threadIdx.x;
    const int wave = tid >> 6, lane = tid & 63;
    const int r0 = by * BROWS, w0 = bx * BCOLS;
    const int zbase = z * 128;

    // ---- A staging: round u: dest byte = u*1024 + 4*tid -> pos = tid>>1, half = tid&1 ----
    const int apos = tid >> 1, ahalf = tid & 1;
    const int aprow = apos >> 5, apcol = apos & 31;
    const int Sp = apcol & 3;                        // col mod 4 -> shifted copy (4B align)
    const int a_toff = Sp * (3 * HH * WW) + aprow * WW + (apcol - Sp) + ahalf * 4;

    // ---- B staging: wave w stages planes w and w+4; 1KB contiguous per plane ----
    const uchar_t* gb = bmk + zbase * 8 + lane * 16; // per-lane global (coalesced)

    const int l31 = lane & 31, h = lane >> 5;
    const int wm = wave >> 1, wn = wave & 1;

    v16f acc[2][2];
    #pragma unroll
    for (int a = 0; a < 2; a++)
        #pragma unroll
        for (int b = 0; b < 2; b++)
            #pragma unroll
            for (int r = 0; r < 16; r++) acc[a][b][r] = 0.f;

    const uchar_t* abase = y4 + (size_t)r0 * WW + w0;    // octet cursor (c=0,i=0,j=0)
    int jc = 0, ic = 0;                                  // uniform cursor (SALU)

    auto stage = [&](int s, int buf) {                   // issue 10 DMAs for slice s -> buf
        uchar_t* ad = Ab + buf * 8192 + wave * 256;
        #pragma unroll
        for (int u = 0; u < 8; u++) {                    // A octets (8 x 1KB)
            gload4(abase + a_toff, ad + u * 1024);
            abase += 8;
            if (++jc == 3) {
                jc = 0; abase += WW - 24;
                if (++ic == 24) { ic = 0; abase += (size_t)(HH - 24) * WW; }
            }
        }
        uchar_t* bd = Bb + buf * 8192 + wave * 1024;
        gload16(gb + (size_t)(s * 8 + wave) * (NP * 8),     bd);          // B plane w
        gload16(gb + (size_t)(s * 8 + wave + 4) * (NP * 8), bd + 4096);   // B plane w+4
    };

    stage(0, 0);                                         // prologue (no readers yet)

    #pragma unroll 1
    for (int s = 0; s < NSTEP; s++) {
        __syncthreads();     // vmcnt(0) drain -> buf[s&1] staged; lgkm drain -> old readers done
        if (s + 1 < NSTEP) stage(s + 1, (s + 1) & 1);    // prefetch overlaps compute below
        const uchar_t* Ac = Ab + (s & 1) * 8192;
        const uchar_t* Bc = Bb + (s & 1) * 8192;

        ll_t af[2][4], bf[2][4];
        #pragma unroll
        for (int mt = 0; mt < 2; mt++)
            #pragma unroll
            for (int ks = 0; ks < 4; ks++)
                af[mt][ks] = *(const ll_t*)(Ac + (ks * 2 + h) * 1024 + (wm * 64 + mt * 32 + l31) * 8);
        #pragma unroll
        for (int nt = 0; nt < 2; nt++)
            #pragma unroll
            for (int ks = 0; ks < 4; ks++)
                bf[nt][ks] = *(const ll_t*)(Bc + (ks * 2 + h) * 1024 + (wn * 64 + nt * 32 + l31) * 8);
        #pragma unroll
        for (int ks = 0; ks < 4; ks++)
            #pragma unroll
            for (int mt = 0; mt < 2; mt++)
                #pragma unroll
                for (int nt = 0; nt < 2; nt++)
                    acc[mt][nt] = __builtin_amdgcn_mfma_f32_32x32x16_fp8_fp8(
                        af[mt][ks], bf[nt][ks], acc[mt][nt], 0, 0, 0);
    }

    // epilogue: approx score + per-(patch, block) max
    float mx0 = mx[zbase + wn * 64 + l31];
    float mx1 = mx[zbase + wn * 64 + 32 + l31];
    float best0 = -1e30f, best1 = -1e30f;
    #pragma unroll
    for (int mt = 0; mt < 2; mt++) {
        #pragma unroll
        for (int r = 0; r < 16; r++) {
            int row32 = (r & 3) + 8 * (r >> 2) + 4 * h;   // 32x32 C/D row (m74/m101)
            int posid = wm * 64 + mt * 32 + row32;
            int rg = r0 + (posid >> 5), wg = w0 + (posid & 31);
            bool valid = (rg < HC) && (wg < WC);
            int pos = rg * WC + wg;
            float S1 = valid ? bf2f(s1m[pos]) : 0.f;
            float iv = valid ? bf2f(ivm[pos]) : 0.f;
            float sc0 = valid ? (acc[mt][0][r] - mx0 * S1) * iv : -1e30f;
            float sc1 = valid ? (acc[mt][1][r] - mx1 * S1) * iv : -1e30f;
            best0 = fmaxf(best0, sc0);
            best1 = fmaxf(best1, sc1);
        }
    }
    best0 = fmaxf(best0, __shfl_xor(best0, 32));         // reduce over h
    best1 = fmaxf(best1, __shfl_xor(best1, 32));
    __syncthreads();                                     // full drain; Ab reused as red
    if (h == 0) {
        red[(wn * 64 + l31) * 2 + wm]      = best0;
        red[(wn * 64 + 32 + l31) * 2 + wm] = best1;
    }
    __syncthreads();
    if (tid < 128)
        ps16[(by * NBX + bx) * NP + zbase + tid] = f2bf(fmaxf(red[tid * 2], red[tid * 2 + 1]));
}

// -------------------- per-patch top-8 blocks --------------------

__global__ void k_select(const ushort_t* __restrict__ ps16, int* __restrict__ cand) {
    int p = blockIdx.x, tid = threadIdx.x;
    __shared__ float ls[NBLK];
    __shared__ float rs[256];
    __shared__ int   ri[256];
    for (int e = tid; e < NBLK; e += 256) ls[e] = bf2f(ps16[e * NP + p]);
    __syncthreads();
    for (int round = 0; round < NCAND; round++) {
        float bs = -1e38f; int bi = 0;
        for (int e = tid; e < NBLK; e += 256) if (ls[e] > bs) { bs = ls[e]; bi = e; }
        rs[tid] = bs; ri[tid] = bi; __syncthreads();
        for (int st = 128; st > 0; st >>= 1) {
            if (tid < st && rs[tid + st] > rs[tid]) { rs[tid] = rs[tid + st]; ri[tid] = ri[tid + st]; }
            __syncthreads();
        }
        int win = ri[0];
        if (tid == 0) cand[p * NCAND + round] = win;
        if (tid == (win & 255)) ls[win] = -1e38f;
        __syncthreads();
    }
}

// -------------------- exact fp32 rescore (recomputes window sums) + gather --------------------

__global__ void k_rescore(const int* __restrict__ cand, const float* __restrict__ xdec,
                          const float* __restrict__ ydec, const float* __restrict__ mx,
                          const float* __restrict__ yfull, float* __restrict__ out) {
    int p = blockIdx.x, tid = threadIdx.x;
    int pr = p >> 4, pc = p & 15;
    float mxp = mx[p];
    float best = -1e30f; int bpos = 0x7FFFFFFF;
    #pragma unroll 1
    for (int cdp = 0; cdp < 4; cdp++) {
        int cd = cdp * 2 + (tid >> 7);
        int blk = cand[p * NCAND + cd];
        int r0 = (blk / NBX) * BROWS, w0 = (blk % NBX) * BCOLS;
        int pi = tid & 127;
        int rg = r0 + (pi >> 5), wg = w0 + (pi & 31);
        if (rg < HC && wg < WC) {
            float sxy = 0.f, sy = 0.f, sy2 = 0.f;
            for (int c = 0; c < CH; c++) {
                #pragma unroll 1
                for (int i = 0; i < KS; i++) {
                    const float* yr = ydec + (c * HH + rg + i) * WW + wg;
                    const float* xr = xdec + (c * XH + pr * KS + i) * XW + pc * KS;
                    #pragma unroll
                    for (int j = 0; j < KS; j++) {
                        float yv = yr[j];
                        sxy = fmaf(yv, xr[j], sxy);
                        sy += yv;
                        sy2 = fmaf(yv, yv, sy2);
                    }
                }
            }
            float d2 = sy2 - sy * sy * (1.0f / 576.0f);
            int pos = rg * WC + wg;
            float sc = (sxy - mxp * sy) * rsqrtf(fmaxf(d2, 1e-20f));
            if (sc > best || (sc == best && pos < bpos)) { best = sc; bpos = pos; }
        }
    }
    __shared__ float rs[256];
    __shared__ int   ri[256];
    rs[tid] = best; ri[tid] = bpos; __syncthreads();
    for (int st = 128; st > 0; st >>= 1) {
        if (tid < st) {
            if (rs[tid + st] > rs[tid] || (rs[tid + st] == rs[tid] && ri[tid + st] < ri[tid])) {
                rs[tid] = rs[tid + st]; ri[tid] = ri[tid + st];
            }
        }
        __syncthreads();
    }
    int bestpos = ri[0];
    int row = bestpos / WC, col = bestpos % WC;
    for (int e = tid; e < CH * KS * KS; e += 256) {
        int c = e / (KS * KS), rem = e % (KS * KS), i = rem / KS, j = rem % KS;
        out[p * CH * KS * KS + e] = yfull[(c * HH + row + i) * WW + col + j];
    }
}

// -------------------- launch --------------------
// ws footprint unchanged from the passing R9/R10: 11.5 MB writes, <12 MB transient reads.

extern "C" void kernel_launch(void* const* d_in, const int* in_sizes, int n_in,
                              void* d_out, int out_size, void* d_ws, size_t ws_size,
                              hipStream_t stream) {
    const float* xdec = (const float*)d_in[0];   // (1,3,384,384)
    const float* ydec = (const float*)d_in[1];   // (1,3,768,768)
    const float* y    = (const float*)d_in[2];   // (1,3,768,768)
    float* out = (float*)d_out;                  // (256,3,24,24)

    float* ws = (float*)d_ws;
    ushort_t* s1m16 = (ushort_t*)(ws + 0);         // 555025 u16
    ushort_t* ivm16 = (ushort_t*)(ws + 277520);    // 555025 u16
    float*    mx    = ws + 555040;                 // 256
    uchar_t*  Bmk   = (uchar_t*)(ws + 555296);     // 442368 B, k-major (16B-aligned)
    int*      cand  = (int*)(ws + 665888);         // 2048
    ushort_t* ps16  = (ushort_t*)(ws + 667936);    // 1,148,928 u16 [blk][pat]
    uchar_t*  y4    = (uchar_t*)(ws + 1242400);    // 7,077,888 B (16B-aligned)
    // box-sum temps alias ps16+y4 region (dead before k_y4/k_corr):
    float* ksum  = ws + 667936;                    // 589824
    float* ksum2 = ws + 1257760;                   // 589824
    float* h1    = ws + 1847584;                   // 572160
    float* h2    = ws + 2419744;                   // 572160 (end 2,991,904 < 3,011,872)

    k_colsum<<<(HH * WW + 255) / 256, 256, 0, stream>>>(ydec, ksum, ksum2);
    k_hsum<<<(HH * WC + 255) / 256, 256, 0, stream>>>(ksum, ksum2, h1, h2);
    k_vsum<<<(HC * WC + 255) / 256, 256, 0, stream>>>(h1, h2, s1m16, ivm16);
    k_meanx<<<NP, 256, 0, stream>>>(xdec, mx);
    k_bmat8<<<NP, 256, 0, stream>>>(xdec, Bmk);
    k_y4<<<(4 * 3 * HH * (WW / 4) + 255) / 256, 256, 0, stream>>>(ydec, y4);

    k_corr<<<NGRID, 256, 0, stream>>>(y4, Bmk, s1m16, ivm16, mx, ps16);
    k_select<<<NP, 256, 0, stream>>>(ps16, cand);
    k_rescore<<<NP, 256, 0, stream>>>(cand, xdec, ydec, mx, y, out);
}

// Round 12
// 685.904 us; speedup vs baseline: 1.3010x; 1.3010x over previous
//
#include <hip/hip_runtime.h>

typedef float v16f __attribute__((ext_vector_type(16)));
typedef unsigned short ushort_t;
typedef unsigned char uchar_t;
typedef long long ll_t;

#define HH 768
#define WW 768
#define CH 3
#define KS 24
#define HC 745
#define WC 745
#define NP 256
#define XH 384
#define XW 384

#define NBX 24            // ceil(745/32)
#define NBY 187           // ceil(745/4)
#define NBLK (NBX*NBY)    // 4488
#define BROWS 4
#define BCOLS 32
#define NSTEP 27          // K=1728 in 64-wide slices (8 octets each)
#define NCAND 8
#define NGRID (8*1152)    // XCD-banded launch (some idle)

// async global->LDS DMA; LDS dest = wave-uniform base + lane*size (global addr per-lane)
__device__ __forceinline__ void gload16(const uchar_t* g, uchar_t* l) {
    __builtin_amdgcn_global_load_lds(
        (const __attribute__((address_space(1))) unsigned int*)(const void*)g,
        (__attribute__((address_space(3))) unsigned int*)(void*)l, 16, 0, 0);
}
__device__ __forceinline__ ushort_t f2bf(float f) {
    union { __bf16 h; ushort_t u; } cv; cv.h = (__bf16)f; return cv.u;
}
__device__ __forceinline__ float bf2f(ushort_t u) {
    union { unsigned u; float f; } cv; cv.u = ((unsigned)u) << 16; return cv.f;
}
// fp32 -> OCP e4m3fn (RNE for normals; grid-round for subnormals). Screen-only precision.
__device__ __forceinline__ uchar_t f2e4m3(float f) {
    unsigned u = __float_as_uint(f);
    unsigned s = (u >> 24) & 0x80;
    float a = fabsf(f);
    if (a < 0.0078125f) {
        int q = (int)(a * 512.0f + 0.5f);
        return (uchar_t)(s | (unsigned)q);
    }
    int e = (int)((u >> 23) & 0xFF);
    unsigned m = (u >> 20) & 7;
    unsigned rest = u & 0xFFFFF;
    if (rest > 0x80000 || (rest == 0x80000 && (m & 1))) { m++; if (m == 8) { m = 0; e++; } }
    int e8 = e - 120;
    if (e8 <= 0) { int q = (int)(a * 512.0f + 0.5f); if (q > 7) q = 7; return (uchar_t)(s | q); }
    if (e8 > 15) return (uchar_t)(s | 0x7E);
    return (uchar_t)(s | ((unsigned)e8 << 3) | m);
}

// -------------------- prep kernels --------------------

__global__ void k_colsum(const float* __restrict__ y, float* __restrict__ ksum,
                         float* __restrict__ ksum2) {
    int idx = blockIdx.x * 256 + threadIdx.x;
    if (idx >= HH * WW) return;
    float a = y[idx], b = y[idx + HH * WW], c = y[idx + 2 * HH * WW];
    ksum[idx]  = a + b + c;
    ksum2[idx] = a * a + b * b + c * c;
}

__global__ void k_hsum(const float* __restrict__ ksum, const float* __restrict__ ksum2,
                       float* __restrict__ h1, float* __restrict__ h2) {
    int idx = blockIdx.x * 256 + threadIdx.x;
    if (idx >= HH * WC) return;
    int h = idx / WC, w = idx % WC;
    const float* r  = ksum  + h * WW + w;
    const float* r2 = ksum2 + h * WW + w;
    float s = 0.f, s2 = 0.f;
    #pragma unroll
    for (int j = 0; j < KS; j++) { s += r[j]; s2 += r2[j]; }
    h1[idx] = s; h2[idx] = s2;
}

// bf16 maps are ONLY used for the approximate pre-screen; k_rescore recomputes exactly.
__global__ void k_vsum(const float* __restrict__ h1, const float* __restrict__ h2,
                       ushort_t* __restrict__ s1m, ushort_t* __restrict__ ivm) {
    int idx = blockIdx.x * 256 + threadIdx.x;
    if (idx >= HC * WC) return;
    int r = idx / WC, w = idx % WC;
    float s = 0.f, s2 = 0.f;
    #pragma unroll
    for (int i = 0; i < KS; i++) { s += h1[(r + i) * WC + w]; s2 += h2[(r + i) * WC + w]; }
    float d2 = s2 - s * s * (1.0f / 576.0f);
    s1m[idx] = f2bf(s);
    ivm[idx] = f2bf(rsqrtf(fmaxf(d2, 1e-20f)));
}

__global__ void k_meanx(const float* __restrict__ x, float* __restrict__ mx) {
    int p = blockIdx.x;
    int pr = p >> 4, pc = p & 15;
    float s = 0.f;
    for (int e = threadIdx.x; e < CH * KS * KS; e += 256) {
        int c = e / (KS * KS); int rem = e % (KS * KS);
        int i = rem / KS, j = rem % KS;
        s += x[(c * XH + pr * KS + i) * XW + pc * KS + j];
    }
    __shared__ float red[256];
    red[threadIdx.x] = s; __syncthreads();
    for (int st = 128; st > 0; st >>= 1) {
        if (threadIdx.x < st) red[threadIdx.x] += red[threadIdx.x + st];
        __syncthreads();
    }
    if (threadIdx.x == 0) mx[p] = red[0] * (1.0f / 1728.0f);
}

// fp8 patch matrix, K-REORDERED j-octet-major: plane o' = (j/8)*72 + c*24 + i.
// Sum over k is order-independent, and this makes the A-side LDS-band address affine.
__global__ void k_bmat8(const float* __restrict__ x, uchar_t* __restrict__ bmk) {
    int p = blockIdx.x; int pr = p >> 4, pc = p & 15;
    for (int e = threadIdx.x; e < CH * KS * KS; e += 256) {
        int c = e / (KS * KS), rem = e % (KS * KS), i = rem / KS, j = rem % KS;
        bmk[((j >> 3) * 72 + c * 24 + i) * (NP * 8) + p * 8 + (j & 7)] =
            f2e4m3(x[(c * XH + pr * KS + i) * XW + pc * KS + j]);
    }
}

// 4 column-shifted fp8 copies: y4[S][c][r][t] = fp8(ydec[c][r][t+S]), S in 0..3, 0-pad OOB.
__global__ void k_y4(const float* __restrict__ yd, uchar_t* __restrict__ y4) {
    int idx = blockIdx.x * 256 + threadIdx.x;
    if (idx >= 4 * 3 * HH * (WW / 4)) return;
    int q = idx % (WW / 4); int rem = idx / (WW / 4);
    int r = rem % HH; rem /= HH;
    int c = rem % 3; int S = rem / 3;
    const float* src = yd + (c * HH + r) * WW;
    union { uchar_t u[4]; unsigned v; } o;
    #pragma unroll
    for (int qq = 0; qq < 4; qq++) {
        int t = q * 4 + qq + S;
        o.u[qq] = f2e4m3(t < WW ? src[t] : 0.f);
    }
    ((unsigned*)(y4 + ((size_t)(S * 3 + c) * HH + r) * WW))[q] = o.v;
}

// -------------------- main MFMA correlation kernel (fp8, band-A, barrier-free) --------------------
// 256 thr (4 waves); XCD-banded flat grid (R10). Tile = 128 pos x 128 pat; wave tile 64x64
// of mfma_f32_32x32x16_fp8_fp8.
//  * A: the tile's ENTIRE K=1728 A-data is one 3x28x56 pixel band (4.7 KB; im2col dup 47x).
//    Loaded ONCE into LDS as 4 column-shifted copies (stride 4768 B: word-stride 1192 = 8 mod 32
//    -> each frag read covers all 32 banks exactly once, conflict-free). Per-slice A address is
//    lane_const + U(s): ONE v_add per slice.
//  * B: wave-PRIVATE tiles (each wave stages only its 64 patches: 4 KB via 4 coalesced gload16,
//    double-buffered) -> no cross-wave dependency -> ZERO barriers in the K-loop; per-wave
//    s_waitcnt vmcnt(4) is the only sync (prefetch stays in flight, never drained to 0).

__global__ __launch_bounds__(256, 3) void k_corr(
    const uchar_t* __restrict__ y4, const uchar_t* __restrict__ bmk,
    const ushort_t* __restrict__ s1m, const ushort_t* __restrict__ ivm,
    const float* __restrict__ mx, ushort_t* __restrict__ ps16)
{
    // ---- XCD-band mapping (heuristic blk%8 -> XCD; wrong mapping only costs speed) ----
    const int xcd = blockIdx.x & 7;
    const int idx = blockIdx.x >> 3;
    const int bstart = (187 * xcd) >> 3;
    const int bcnt = ((187 * (xcd + 1)) >> 3) - bstart;
    const int local_by = idx / 48;
    if (local_by >= bcnt) return;                    // idle filler block (no barriers follow for it)
    const int rem = idx - local_by * 48;
    const int z = rem / 24;                          // patch half
    const int bx = rem - z * 24;
    const int by = bstart + local_by;

    __shared__ __align__(16) uchar_t Aband[19072];   // 4 copies x 84 rows x 56 B (stride 4768)
    __shared__ __align__(16) uchar_t Bb[32768];      // 2 buf x 4 waves x [8 planes][64 pat][8B]
    float* red = (float*)Aband;                      // epilogue-only alias (post-sync)

    const int tid = threadIdx.x;
    const int wave = tid >> 6, lane = tid & 63;
    const int r0 = by * BROWS, w0 = bx * BCOLS;
    const int zbase = z * 128;
    const int l31 = lane & 31, h = lane >> 5;
    const int wm = wave >> 1, wn = wave & 1;

    // ---- prologue: load A band (rows r0..r0+27, cols w0..w0+55) from the 4 shifted planes ----
    for (int e = tid; e < 4704; e += 256) {          // 4 copies x 84 rows x 14 dwords
        int dw = e % 14;
        int row84 = (e / 14) % 84;
        int S = e / (14 * 84);
        int c = row84 / 28, r = row84 - c * 28;
        int gr = r0 + r; gr = gr < HH ? gr : HH - 1; // clamp feeds only masked-invalid positions
        unsigned v = *(const unsigned*)(y4 + ((size_t)(S * 3 + c) * HH + gr) * WW + w0 + dw * 4);
        *(unsigned*)(Aband + S * 4768 + row84 * 56 + dw * 4) = v;
    }

    // ---- B staging (wave-private): lane l covers plane 2u+(l>>5), patches 2(l&31)..+1 ----
    const uchar_t* gB = bmk + (lane >> 5) * 2048 + (size_t)(zbase + wn * 64) * 8 + (lane & 31) * 16;
    uchar_t* bwave = Bb + wave * 4096;
    auto stageB = [&](int s, int buf) {
        uchar_t* bd = bwave + buf * 16384;
        const uchar_t* g = gB + (size_t)s * 16384;
        gload16(g,         bd);                      // planes 0,1 of slice
        gload16(g + 4096,  bd + 1024);               // planes 2,3
        gload16(g + 8192,  bd + 2048);               // planes 4,5
        gload16(g + 12288, bd + 3072);               // planes 6,7
    };

    stageB(0, 0);

    // A frag lane base: addr = sh*4768 + (c*28 + pr+ibase+2ks+h)*56 + (l31 + jo*8 - sh)
    //                 = [sh*4767 + l31 + (wm*2+h)*56] + U(s) + mt*56 + ks*112   (j0 = jo*8 = 0 mod 4
    //                   -> shift copy sh = l31&3 is lane-constant)
    const uchar_t* Abase0 = Aband + (l31 & 3) * 4767 + l31 + (wm * 2 + h) * 56;

    v16f acc[2][2];
    #pragma unroll
    for (int a = 0; a < 2; a++)
        #pragma unroll
        for (int b = 0; b < 2; b++)
            #pragma unroll
            for (int r = 0; r < 16; r++) acc[a][b][r] = 0.f;

    __syncthreads();                                 // band visible to all waves (one-time)

    int U = 0, j3 = 0, c3 = 0;                       // uniform cursor: U = c*1568 + ibase*56 + jo*8
    #pragma unroll 1
    for (int s = 0; s < NSTEP; s++) {
        if (s + 1 < NSTEP) {
            stageB(s + 1, (s + 1) & 1);              // 4 new DMAs in flight
            asm volatile("s_waitcnt vmcnt(4)" ::: "memory");   // slice-s's 4 (older) landed
        } else {
            asm volatile("s_waitcnt vmcnt(0)" ::: "memory");
        }
        const uchar_t* Ap = Abase0 + U;
        const uchar_t* Bp = bwave + (s & 1) * 16384 + h * 512 + l31 * 8;

        ll_t af[2][4], bf[2][4];
        #pragma unroll
        for (int ks = 0; ks < 4; ks++) {
            unsigned lo0 = *(const unsigned*)(Ap + ks * 112);
            unsigned hi0 = *(const unsigned*)(Ap + ks * 112 + 4);
            unsigned lo1 = *(const unsigned*)(Ap + ks * 112 + 56);
            unsigned hi1 = *(const unsigned*)(Ap + ks * 112 + 60);
            af[0][ks] = (ll_t)(((unsigned long long)hi0 << 32) | (unsigned long long)lo0);
            af[1][ks] = (ll_t)(((unsigned long long)hi1 << 32) | (unsigned long long)lo1);
            bf[0][ks] = *(const ll_t*)(Bp + ks * 1024);
            bf[1][ks] = *(const ll_t*)(Bp + ks * 1024 + 256);
        }
        #pragma unroll
        for (int ks = 0; ks < 4; ks++)
            #pragma unroll
            for (int mt = 0; mt < 2; mt++)
                #pragma unroll
                for (int nt = 0; nt < 2; nt++)
                    acc[mt][nt] = __builtin_amdgcn_mfma_f32_32x32x16_fp8_fp8(
                        af[mt][ks], bf[nt][ks], acc[mt][nt], 0, 0, 0);

        if (++j3 < 3) U += 448;                      // ibase += 8
        else { j3 = 0; if (++c3 < 3) U += 672;       // c += 1, ibase -> 0
               else { c3 = 0; U -= 4024; } }         // jo += 1, c -> 0
    }

    // epilogue: approx score + per-(patch, block) max
    float mx0 = mx[zbase + wn * 64 + l31];
    float mx1 = mx[zbase + wn * 64 + 32 + l31];
    float best0 = -1e30f, best1 = -1e30f;
    #pragma unroll
    for (int mt = 0; mt < 2; mt++) {
        #pragma unroll
        for (int r = 0; r < 16; r++) {
            int row32 = (r & 3) + 8 * (r >> 2) + 4 * h;   // 32x32 C/D row (m74/m101)
            int posid = wm * 64 + mt * 32 + row32;
            int rg = r0 + (posid >> 5), wg = w0 + (posid & 31);
            bool valid = (rg < HC) && (wg < WC);
            int pos = rg * WC + wg;
            float S1 = valid ? bf2f(s1m[pos]) : 0.f;
            float iv = valid ? bf2f(ivm[pos]) : 0.f;
            float sc0 = valid ? (acc[mt][0][r] - mx0 * S1) * iv : -1e30f;
            float sc1 = valid ? (acc[mt][1][r] - mx1 * S1) * iv : -1e30f;
            best0 = fmaxf(best0, sc0);
            best1 = fmaxf(best1, sc1);
        }
    }
    best0 = fmaxf(best0, __shfl_xor(best0, 32));     // reduce over h
    best1 = fmaxf(best1, __shfl_xor(best1, 32));
    __syncthreads();                                 // all compute done; Aband reused as red
    if (h == 0) {
        red[(wn * 64 + l31) * 2 + wm]      = best0;
        red[(wn * 64 + 32 + l31) * 2 + wm] = best1;
    }
    __syncthreads();
    if (tid < 128)
        ps16[(by * NBX + bx) * NP + zbase + tid] = f2bf(fmaxf(red[tid * 2], red[tid * 2 + 1]));
}

// -------------------- per-patch top-8 blocks --------------------

__global__ void k_select(const ushort_t* __restrict__ ps16, int* __restrict__ cand) {
    int p = blockIdx.x, tid = threadIdx.x;
    __shared__ float ls[NBLK];
    __shared__ float rs[256];
    __shared__ int   ri[256];
    for (int e = tid; e < NBLK; e += 256) ls[e] = bf2f(ps16[e * NP + p]);
    __syncthreads();
    for (int round = 0; round < NCAND; round++) {
        float bs = -1e38f; int bi = 0;
        for (int e = tid; e < NBLK; e += 256) if (ls[e] > bs) { bs = ls[e]; bi = e; }
        rs[tid] = bs; ri[tid] = bi; __syncthreads();
        for (int st = 128; st > 0; st >>= 1) {
            if (tid < st && rs[tid + st] > rs[tid]) { rs[tid] = rs[tid + st]; ri[tid] = ri[tid + st]; }
            __syncthreads();
        }
        int win = ri[0];
        if (tid == 0) cand[p * NCAND + round] = win;
        if (tid == (win & 255)) ls[win] = -1e38f;
        __syncthreads();
    }
}

// -------------------- exact fp32 rescore (recomputes window sums) + gather --------------------

__global__ void k_rescore(const int* __restrict__ cand, const float* __restrict__ xdec,
                          const float* __restrict__ ydec, const float* __restrict__ mx,
                          const float* __restrict__ yfull, float* __restrict__ out) {
    int p = blockIdx.x, tid = threadIdx.x;
    int pr = p >> 4, pc = p & 15;
    float mxp = mx[p];
    float best = -1e30f; int bpos = 0x7FFFFFFF;
    #pragma unroll 1
    for (int cdp = 0; cdp < 4; cdp++) {
        int cd = cdp * 2 + (tid >> 7);
        int blk = cand[p * NCAND + cd];
        int r0 = (blk / NBX) * BROWS, w0 = (blk % NBX) * BCOLS;
        int pi = tid & 127;
        int rg = r0 + (pi >> 5), wg = w0 + (pi & 31);
        if (rg < HC && wg < WC) {
            float sxy = 0.f, sy = 0.f, sy2 = 0.f;
            for (int c = 0; c < CH; c++) {
                #pragma unroll 1
                for (int i = 0; i < KS; i++) {
                    const float* yr = ydec + (c * HH + rg + i) * WW + wg;
                    const float* xr = xdec + (c * XH + pr * KS + i) * XW + pc * KS;
                    #pragma unroll
                    for (int j = 0; j < KS; j++) {
                        float yv = yr[j];
                        sxy = fmaf(yv, xr[j], sxy);
                        sy += yv;
                        sy2 = fmaf(yv, yv, sy2);
                    }
                }
            }
            float d2 = sy2 - sy * sy * (1.0f / 576.0f);
            int pos = rg * WC + wg;
            float sc = (sxy - mxp * sy) * rsqrtf(fmaxf(d2, 1e-20f));
            if (sc > best || (sc == best && pos < bpos)) { best = sc; bpos = pos; }
        }
    }
    __shared__ float rs[256];
    __shared__ int   ri[256];
    rs[tid] = best; ri[tid] = bpos; __syncthreads();
    for (int st = 128; st > 0; st >>= 1) {
        if (tid < st) {
            if (rs[tid + st] > rs[tid] || (rs[tid + st] == rs[tid] && ri[tid + st] < ri[tid])) {
                rs[tid] = rs[tid + st]; ri[tid] = ri[tid + st];
            }
        }
        __syncthreads();
    }
    int bestpos = ri[0];
    int row = bestpos / WC, col = bestpos % WC;
    for (int e = tid; e < CH * KS * KS; e += 256) {
        int c = e / (KS * KS), rem = e % (KS * KS), i = rem / KS, j = rem % KS;
        out[p * CH * KS * KS + e] = yfull[(c * HH + row + i) * WW + col + j];
    }
}

// -------------------- launch --------------------
// ws footprint: 11.5 MB writes; transient OOB reads (band-load tail, masked-invalid rows)
// reach <12.1 MB — safely under the >=13.7 MB proven by R1-R3.

extern "C" void kernel_launch(void* const* d_in, const int* in_sizes, int n_in,
                              void* d_out, int out_size, void* d_ws, size_t ws_size,
                              hipStream_t stream) {
    const float* xdec = (const float*)d_in[0];   // (1,3,384,384)
    const float* ydec = (const float*)d_in[1];   // (1,3,768,768)
    const float* y    = (const float*)d_in[2];   // (1,3,768,768)
    float* out = (float*)d_out;                  // (256,3,24,24)

    float* ws = (float*)d_ws;
    ushort_t* s1m16 = (ushort_t*)(ws + 0);         // 555025 u16
    ushort_t* ivm16 = (ushort_t*)(ws + 277520);    // 555025 u16
    float*    mx    = ws + 555040;                 // 256
    uchar_t*  Bmk   = (uchar_t*)(ws + 555296);     // 442368 B, k-major reordered (16B-aligned)
    int*      cand  = (int*)(ws + 665888);         // 2048
    ushort_t* ps16  = (ushort_t*)(ws + 667936);    // 1,148,928 u16 [blk][pat]
    uchar_t*  y4    = (uchar_t*)(ws + 1242400);    // 7,077,888 B (16B-aligned)
    // box-sum temps alias ps16+y4 region (dead before k_y4/k_corr):
    float* ksum  = ws + 667936;                    // 589824
    float* ksum2 = ws + 1257760;                   // 589824
    float* h1    = ws + 1847584;                   // 572160
    float* h2    = ws + 2419744;                   // 572160 (end 2,991,904 < 3,011,872)

    k_colsum<<<(HH * WW + 255) / 256, 256, 0, stream>>>(ydec, ksum, ksum2);
    k_hsum<<<(HH * WC + 255) / 256, 256, 0, stream>>>(ksum, ksum2, h1, h2);
    k_vsum<<<(HC * WC + 255) / 256, 256, 0, stream>>>(h1, h2, s1m16, ivm16);
    k_meanx<<<NP, 256, 0, stream>>>(xdec, mx);
    k_bmat8<<<NP, 256, 0, stream>>>(xdec, Bmk);
    k_y4<<<(4 * 3 * HH * (WW / 4) + 255) / 256, 256, 0, stream>>>(ydec, y4);

    k_corr<<<NGRID, 256, 0, stream>>>(y4, Bmk, s1m16, ivm16, mx, ps16);
    k_select<<<NP, 256, 0, stream>>>(ps16, cand);
    k_rescore<<<NP, 256, 0, stream>>>(cand, xdec, ydec, mx, y, out);
}